// Round 6
// baseline (683.418 us; speedup 1.0000x reference)
//
#include <hip/hip_runtime.h>

#define EPSILON 1e-6f
#define NADMIN 256
#define NBATCH 16
#define NPIX (1024 * 1024)    // H*W per batch
#define NSPLIT 8              // global histogram copies (contention spreading)
#define UNROLL 4

// ---------------------------------------------------------------------------
// Pass 0: zero the split histograms with plain stores (graph/replay-safe:
// no memset node, no cross-call state; every byte overwritten every call).
// ---------------------------------------------------------------------------
__global__ __launch_bounds__(256) void zero_kernel(float* __restrict__ Sg)
{
    int i = blockIdx.x * blockDim.x + threadIdx.x;
    if (i < NSPLIT * NBATCH * NADMIN) Sg[i] = 0.0f;
}

// ---------------------------------------------------------------------------
// Pass 1: per-pixel fire-and-forget GLOBAL atomics (bypasses the DS unit,
// which lane-serializes scattered ops at ~3 cyc/lane => ~84us floor).
// Global atomic adds have no return dependency -> pure issue-rate bound.
// 8-way split histogram caps same-address serialization at ~460 atomics/addr.
// grid = (64, NBATCH), block = 256 -> 16 float4/thread, 4 iters of UNROLL 4.
// ---------------------------------------------------------------------------
__global__ __launch_bounds__(256) void atomic_segsum_kernel(
    const float* __restrict__ P,
    const int* __restrict__ ids,
    float* __restrict__ Sg)
{
    const int b = blockIdx.y;
    const int split = blockIdx.x & (NSPLIT - 1);
    float* __restrict__ Sb = Sg + ((size_t)split * NBATCH + b) * NADMIN;

    const float4* __restrict__ p4  = (const float4*)(P   + (size_t)b * NPIX);
    const int4*   __restrict__ id4 = (const int4*)  (ids + (size_t)b * NPIX);
    const int nvec = NPIX / 4;                      // 262144
    const int stride = gridDim.x * blockDim.x;      // 16384

    int i = blockIdx.x * blockDim.x + threadIdx.x;
    for (; i + (UNROLL - 1) * stride < nvec; i += UNROLL * stride) {
        float4 p[UNROLL];
        int4   d[UNROLL];
        #pragma unroll
        for (int u = 0; u < UNROLL; ++u) {          // 8 loads in flight first
            p[u] = p4[i + u * stride];
            d[u] = id4[i + u * stride];
        }
        #pragma unroll
        for (int u = 0; u < UNROLL; ++u) {          // fire-and-forget atomics
            if (d[u].x >= 0) atomicAdd(&Sb[d[u].x], p[u].x);
            if (d[u].y >= 0) atomicAdd(&Sb[d[u].y], p[u].y);
            if (d[u].z >= 0) atomicAdd(&Sb[d[u].z], p[u].z);
            if (d[u].w >= 0) atomicAdd(&Sb[d[u].w], p[u].w);
        }
    }
    for (; i < nvec; i += stride) {                 // tail (empty here)
        float4 p = p4[i];
        int4   d = id4[i];
        if (d.x >= 0) atomicAdd(&Sb[d.x], p.x);
        if (d.y >= 0) atomicAdd(&Sb[d.y], p.y);
        if (d.z >= 0) atomicAdd(&Sb[d.z], p.z);
        if (d.w >= 0) atomicAdd(&Sb[d.w], p.w);
    }
}

// ---------------------------------------------------------------------------
// Pass 2: R[b][a] = census[b][a] / (sum_s Sg[s][b][a] + eps).
// Fixed summation order over splits; plain stores only.
// grid = NBATCH, block = NADMIN
// ---------------------------------------------------------------------------
__global__ __launch_bounds__(NADMIN) void reduce_kernel(
    const float* __restrict__ Sg,
    const float* __restrict__ census,
    float* __restrict__ R)
{
    const int b = blockIdx.x;
    const int a = threadIdx.x;
    float sum = 0.0f;
    #pragma unroll
    for (int s = 0; s < NSPLIT; ++s)
        sum += Sg[((size_t)s * NBATCH + b) * NADMIN + a];
    R[b * NADMIN + a] = census[b * NADMIN + a] / (sum + EPSILON);
}

// ---------------------------------------------------------------------------
// Pass 3: out = valid ? p * R[b][id] : p   (unchanged; passed 4 rounds)
// grid = (128, NBATCH), block = 256
// ---------------------------------------------------------------------------
__global__ __launch_bounds__(256) void apply_kernel(
    const float* __restrict__ P,
    const int* __restrict__ ids,
    const float* __restrict__ R,
    float* __restrict__ out)
{
    __shared__ float s_R[NADMIN];
    const int b = blockIdx.y;
    const int t = threadIdx.x;
    if (t < NADMIN) s_R[t] = R[b * NADMIN + t];
    __syncthreads();

    const float4* __restrict__ p4  = (const float4*)(P   + (size_t)b * NPIX);
    const int4*   __restrict__ id4 = (const int4*)  (ids + (size_t)b * NPIX);
    float4* __restrict__ o4 = (float4*)(out + (size_t)b * NPIX);
    const int nvec = NPIX / 4;
    const int stride = gridDim.x * blockDim.x;

    for (int i = blockIdx.x * blockDim.x + t; i < nvec; i += stride) {
        float4 p = p4[i];
        int4   d = id4[i];
        float4 o;
        o.x = (d.x >= 0) ? p.x * s_R[d.x] : p.x;
        o.y = (d.y >= 0) ? p.y * s_R[d.y] : p.y;
        o.z = (d.z >= 0) ? p.z * s_R[d.z] : p.z;
        o.w = (d.w >= 0) ? p.w * s_R[d.w] : p.w;
        o4[i] = o;
    }
}

extern "C" void kernel_launch(void* const* d_in, const int* in_sizes, int n_in,
                              void* d_out, int out_size, void* d_ws, size_t ws_size,
                              hipStream_t stream)
{
    const float* P      = (const float*)d_in[0];   // (B,1,H,W) f32
    const int*   ids    = (const int*)d_in[1];     // (B,H,W) i32
    const float* census = (const float*)d_in[2];   // (B,A) f32
    float* out = (float*)d_out;

    float* Sg = (float*)d_ws;                              // (NSPLIT,B,A) = 128 KB
    float* R  = Sg + (size_t)NSPLIT * NBATCH * NADMIN;     // (B,A)

    zero_kernel<<<dim3((NSPLIT * NBATCH * NADMIN + 255) / 256), dim3(256), 0, stream>>>(Sg);
    atomic_segsum_kernel<<<dim3(64, NBATCH), dim3(256), 0, stream>>>(P, ids, Sg);
    reduce_kernel<<<dim3(NBATCH), dim3(NADMIN), 0, stream>>>(Sg, census, R);
    apply_kernel<<<dim3(128, NBATCH), dim3(256), 0, stream>>>(P, ids, R, out);
}

// Round 7
// 74.757 us; speedup vs baseline: 9.1418x; 9.1418x over previous
//
#include <hip/hip_runtime.h>

#define EPSILON 1e-6f
#define NADMIN 256
#define NBATCH 16
#define NPIX (1024 * 1024)    // H*W per batch
#define SEG_BLOCKS 64         // segsum blocks per batch
#define SEG_THREADS 512
#define NCOPY 4               // histogram copies (indexed by wave&3)
#define HSTRIDE 257           // odd stride: same id -> different bank per copy
#define UNROLL 4
#define SCALE 65536.0f        // fixed-point scale (p in [0,1))

// ---------------------------------------------------------------------------
// Pass 1: per-batch partial segment sums in FIXED-POINT u32 via native
// fire-and-forget ds_add_u32 (integer LDS atomicAdd never lowers to a CAS
// loop and has no return-latency chain -- the suspected cause of the ~82us
// floor of all f32 LDS schemes, r1/r4/r5).
// 4 histogram copies (wave&3, stride 257) cut same-addr + same-bank collisions.
// Exact integer math -> bitwise deterministic across graph replays.
// grid = (SEG_BLOCKS, NBATCH), block = 512 -> 8 iters/thread.
// ---------------------------------------------------------------------------
__global__ __launch_bounds__(SEG_THREADS) void segsum_kernel(
    const float* __restrict__ P,
    const int* __restrict__ ids,
    unsigned int* __restrict__ Spart)
{
    __shared__ unsigned int hist[NCOPY * HSTRIDE];   // ~4.1 KB
    const int b = blockIdx.y;
    const int t = threadIdx.x;

    for (int i = t; i < NCOPY * HSTRIDE; i += SEG_THREADS) hist[i] = 0u;
    __syncthreads();

    unsigned int* __restrict__ h = hist + ((t >> 6) & (NCOPY - 1)) * HSTRIDE;

    const float4* __restrict__ p4  = (const float4*)(P   + (size_t)b * NPIX);
    const int4*   __restrict__ id4 = (const int4*)  (ids + (size_t)b * NPIX);
    const int nvec = NPIX / 4;                      // 262144
    const int stride = gridDim.x * blockDim.x;      // 32768

    int i = blockIdx.x * blockDim.x + t;
    for (; i + (UNROLL - 1) * stride < nvec; i += UNROLL * stride) {
        float4 p[UNROLL];
        int4   d[UNROLL];
        #pragma unroll
        for (int u = 0; u < UNROLL; ++u) {          // issue all loads first
            p[u] = p4[i + u * stride];
            d[u] = id4[i + u * stride];
        }
        #pragma unroll
        for (int u = 0; u < UNROLL; ++u) {          // native ds_add_u32
            if (d[u].x >= 0) atomicAdd(&h[d[u].x], __float2uint_rn(p[u].x * SCALE));
            if (d[u].y >= 0) atomicAdd(&h[d[u].y], __float2uint_rn(p[u].y * SCALE));
            if (d[u].z >= 0) atomicAdd(&h[d[u].z], __float2uint_rn(p[u].z * SCALE));
            if (d[u].w >= 0) atomicAdd(&h[d[u].w], __float2uint_rn(p[u].w * SCALE));
        }
    }
    for (; i < nvec; i += stride) {                 // tail (empty here)
        float4 p = p4[i];
        int4   d = id4[i];
        if (d.x >= 0) atomicAdd(&h[d.x], __float2uint_rn(p.x * SCALE));
        if (d.y >= 0) atomicAdd(&h[d.y], __float2uint_rn(p.y * SCALE));
        if (d.z >= 0) atomicAdd(&h[d.z], __float2uint_rn(p.z * SCALE));
        if (d.w >= 0) atomicAdd(&h[d.w], __float2uint_rn(p.w * SCALE));
    }
    __syncthreads();

    // Per-block total <= 16384 px * 2^16 = 2^30: u32-safe across copies.
    if (t < NADMIN) {
        unsigned int s = 0u;
        #pragma unroll
        for (int c = 0; c < NCOPY; ++c) s += hist[c * HSTRIDE + t];
        Spart[((size_t)b * SEG_BLOCKS + blockIdx.x) * NADMIN + t] = s;
    }
}

// ---------------------------------------------------------------------------
// Pass 2: R[b][a] = census / (sum_blocks Spart / SCALE + eps).
// Integer partials summed exactly in u64; plain stores; deterministic.
// grid = NBATCH, block = NADMIN
// ---------------------------------------------------------------------------
__global__ __launch_bounds__(NADMIN) void reduce_kernel(
    const unsigned int* __restrict__ Spart,
    const float* __restrict__ census,
    float* __restrict__ R)
{
    const int b = blockIdx.x;
    const int a = threadIdx.x;
    const unsigned int* base = Spart + (size_t)b * SEG_BLOCKS * NADMIN + a;
    unsigned long long total = 0ull;
    #pragma unroll 8
    for (int j = 0; j < SEG_BLOCKS; ++j) total += base[j * NADMIN];
    float S = (float)((double)total * (1.0 / SCALE));
    R[b * NADMIN + a] = census[b * NADMIN + a] / (S + EPSILON);
}

// ---------------------------------------------------------------------------
// Pass 3: out = valid ? p * R[b][id] : p   (unchanged; passed 5 rounds)
// grid = (128, NBATCH), block = 256
// ---------------------------------------------------------------------------
__global__ __launch_bounds__(256) void apply_kernel(
    const float* __restrict__ P,
    const int* __restrict__ ids,
    const float* __restrict__ R,
    float* __restrict__ out)
{
    __shared__ float s_R[NADMIN];
    const int b = blockIdx.y;
    const int t = threadIdx.x;
    if (t < NADMIN) s_R[t] = R[b * NADMIN + t];
    __syncthreads();

    const float4* __restrict__ p4  = (const float4*)(P   + (size_t)b * NPIX);
    const int4*   __restrict__ id4 = (const int4*)  (ids + (size_t)b * NPIX);
    float4* __restrict__ o4 = (float4*)(out + (size_t)b * NPIX);
    const int nvec = NPIX / 4;
    const int stride = gridDim.x * blockDim.x;

    for (int i = blockIdx.x * blockDim.x + t; i < nvec; i += stride) {
        float4 p = p4[i];
        int4   d = id4[i];
        float4 o;
        o.x = (d.x >= 0) ? p.x * s_R[d.x] : p.x;
        o.y = (d.y >= 0) ? p.y * s_R[d.y] : p.y;
        o.z = (d.z >= 0) ? p.z * s_R[d.z] : p.z;
        o.w = (d.w >= 0) ? p.w * s_R[d.w] : p.w;
        o4[i] = o;
    }
}

extern "C" void kernel_launch(void* const* d_in, const int* in_sizes, int n_in,
                              void* d_out, int out_size, void* d_ws, size_t ws_size,
                              hipStream_t stream)
{
    const float* P      = (const float*)d_in[0];   // (B,1,H,W) f32
    const int*   ids    = (const int*)d_in[1];     // (B,H,W) i32
    const float* census = (const float*)d_in[2];   // (B,A) f32
    float* out = (float*)d_out;

    unsigned int* Spart = (unsigned int*)d_ws;                 // (B,64,A) u32 = 1 MB
    float* R = (float*)(Spart + (size_t)NBATCH * SEG_BLOCKS * NADMIN);  // (B,A)

    segsum_kernel<<<dim3(SEG_BLOCKS, NBATCH), dim3(SEG_THREADS), 0, stream>>>(P, ids, Spart);
    reduce_kernel<<<dim3(NBATCH), dim3(NADMIN), 0, stream>>>(Spart, census, R);
    apply_kernel<<<dim3(128, NBATCH), dim3(256), 0, stream>>>(P, ids, R, out);
}